// Round 1
// baseline (258.455 us; speedup 1.0000x reference)
//
#include <hip/hip_runtime.h>

#define DDIM 2048
#define BDIM 2048
#define EPS 1e-7f
#define B_CHUNK 16
#define D_PER_BLOCK 256

// Each thread: one d (fixed gate row in 64 VGPRs), loops over B_CHUNK b values.
// Wave = 64 consecutive d -> input loads per (wave, b) span one contiguous
// 1536B chunk; output stores coalesced dwords.
__global__ __launch_bounds__(256, 4)
void lut_layer_kernel(const float* __restrict__ inputs,
                      const float* __restrict__ lut,
                      float* __restrict__ out) {
    const int d  = blockIdx.x * D_PER_BLOCK + threadIdx.x;
    const int b0 = blockIdx.y * B_CHUNK;

    // ---- gate row: g[i] = sigmoid(50 * lut[d][i]) ----
    float g[64];
    const float4* lrow = reinterpret_cast<const float4*>(lut + (size_t)d * 64);
#pragma unroll
    for (int k = 0; k < 16; ++k) {
        float4 v = lrow[k];
        g[4 * k + 0] = 1.0f / (1.0f + __expf(-50.0f * v.x));
        g[4 * k + 1] = 1.0f / (1.0f + __expf(-50.0f * v.y));
        g[4 * k + 2] = 1.0f / (1.0f + __expf(-50.0f * v.z));
        g[4 * k + 3] = 1.0f / (1.0f + __expf(-50.0f * v.w));
    }

    const float* inp = inputs + (size_t)(b0 * DDIM + d) * 6;
    float* op = out + (size_t)b0 * DDIM + d;

#pragma unroll 2
    for (int it = 0; it < B_CHUNK; ++it) {
        const float* e = inp + (size_t)it * DDIM * 6;
        float x0 = e[0], x1 = e[1], x2 = e[2], x3 = e[3], x4 = e[4], x5 = e[5];

        // p_q = relu(concat(1-x, x)) + eps ; hi_j selected when bin bit j
        // (MSB-first) is 1, lo_j when 0.
        float lo0 = fmaxf(x0, 0.f) + EPS, hi0 = fmaxf(1.f - x0, 0.f) + EPS;
        float lo1 = fmaxf(x1, 0.f) + EPS, hi1 = fmaxf(1.f - x1, 0.f) + EPS;
        float lo2 = fmaxf(x2, 0.f) + EPS, hi2 = fmaxf(1.f - x2, 0.f) + EPS;
        float lo3 = fmaxf(x3, 0.f) + EPS, hi3 = fmaxf(1.f - x3, 0.f) + EPS;
        float lo4 = fmaxf(x4, 0.f) + EPS, hi4 = fmaxf(1.f - x4, 0.f) + EPS;
        float lo5 = fmaxf(x5, 0.f) + EPS, hi5 = fmaxf(1.f - x5, 0.f) + EPS;

        // Pair products: index bit1 -> first factor, bit0 -> second.
        float m01[4] = {lo0 * lo1, lo0 * hi1, hi0 * lo1, hi0 * hi1};
        float m23[4] = {lo2 * lo3, lo2 * hi3, hi2 * lo3, hi2 * hi3};
        float m45[4] = {lo4 * lo5, lo4 * hi5, hi4 * lo5, hi4 * hi5};

        // out = sum_{p,q} m01[p]*m23[q]*(sum_r m45[r]*g[p*16+q*4+r])
        float acc = 0.f;
#pragma unroll
        for (int p = 0; p < 4; ++p) {
#pragma unroll
            for (int q = 0; q < 4; ++q) {
                const int base = p * 16 + q * 4;
                float inner = m45[0] * g[base + 0];
                inner = fmaf(m45[1], g[base + 1], inner);
                inner = fmaf(m45[2], g[base + 2], inner);
                inner = fmaf(m45[3], g[base + 3], inner);
                acc = fmaf(m01[p] * m23[q], inner, acc);
            }
        }
        op[(size_t)it * DDIM] = acc;
    }
}

extern "C" void kernel_launch(void* const* d_in, const int* in_sizes, int n_in,
                              void* d_out, int out_size, void* d_ws, size_t ws_size,
                              hipStream_t stream) {
    const float* inputs = (const float*)d_in[0];
    const float* lut    = (const float*)d_in[1];
    // d_in[2] (p_q_2_lut_table) is a deterministic bit-selection table; its
    // structure is folded into the product tree above.
    float* out = (float*)d_out;

    dim3 grid(DDIM / D_PER_BLOCK, BDIM / B_CHUNK);  // (8, 128) = 1024 blocks
    dim3 block(256);
    lut_layer_kernel<<<grid, block, 0, stream>>>(inputs, lut, out);
}

// Round 2
// 185.423 us; speedup vs baseline: 1.3939x; 1.3939x over previous
//
#include <hip/hip_runtime.h>

#define DDIM 2048
#define BDIM 2048
#define EPS 1e-7f
#define DPB 256                 // d-values per block (one per thread)
#define B_CHUNK 16              // b-values per block
#define B_SUB 4                 // b-rows staged in LDS per stage
#define NSTAGE (B_CHUNK / B_SUB)

// Each thread owns one d (gate row in 64 VGPRs), loops over B_CHUNK b.
// Inputs are staged to LDS with fully-coalesced float4 loads (wave w stages
// b-row w: 6 rounds x 64 lanes x 16B = 6KB contiguous), register-prefetched
// one stage ahead so HBM latency hides under compute.
__global__ __launch_bounds__(256)
void lut_layer_kernel(const float* __restrict__ inputs,
                      const float* __restrict__ lut,
                      float* __restrict__ out) {
    __shared__ float sbuf[B_SUB * DPB * 6];   // 24 KB

    const int t    = threadIdx.x;
    const int lane = t & 63;
    const int wrow = t >> 6;                  // wave index = staged b-row
    const int d0   = blockIdx.x * DPB;
    const int b0   = blockIdx.y * B_CHUNK;

    // ---- gate row: g[i] = sigmoid(50 * lut[d][i]) ----
    float g[64];
    {
        const float4* lr = reinterpret_cast<const float4*>(lut + (size_t)(d0 + t) * 64);
#pragma unroll
        for (int k = 0; k < 16; ++k) {
            float4 v = lr[k];
            g[4*k+0] = 1.0f / (1.0f + __expf(-50.0f * v.x));
            g[4*k+1] = 1.0f / (1.0f + __expf(-50.0f * v.y));
            g[4*k+2] = 1.0f / (1.0f + __expf(-50.0f * v.z));
            g[4*k+3] = 1.0f / (1.0f + __expf(-50.0f * v.w));
        }
    }

    const float*  gbase = inputs + ((size_t)b0 * DDIM + d0) * 6;
    const size_t  rstr  = (size_t)DDIM * 6;   // floats between consecutive b

    float4 pf[6];
    auto LOAD_STAGE = [&](int s) {            // issue 6 coalesced dwordx4 per thread
#pragma unroll
        for (int r = 0; r < 6; ++r)
            pf[r] = *reinterpret_cast<const float4*>(
                gbase + (size_t)(s * B_SUB + wrow) * rstr + ((r * 64 + lane) << 2));
    };
    auto WRITE_STAGE = [&]() {                // linear LDS, ds_write_b128
#pragma unroll
        for (int r = 0; r < 6; ++r)
            *reinterpret_cast<float4*>(
                &sbuf[wrow * (DPB * 6) + ((r * 64 + lane) << 2)]) = pf[r];
    };

    LOAD_STAGE(0);
    WRITE_STAGE();
    __syncthreads();

    float* op = out + (size_t)b0 * DDIM + d0 + t;

    for (int s = 0; s < NSTAGE; ++s) {
        if (s + 1 < NSTAGE) LOAD_STAGE(s + 1);   // in flight during compute

#pragma unroll
        for (int bl = 0; bl < B_SUB; ++bl) {
            const float* e = &sbuf[bl * (DPB * 6) + t * 6];
            float x0 = e[0], x1 = e[1], x2 = e[2], x3 = e[3], x4 = e[4], x5 = e[5];

            // p_q = relu(concat(1-x, x)) + eps; hi_j when MSB-first bit j is 1
            float lo0 = fmaxf(x0, 0.f) + EPS, hi0 = fmaxf(1.f - x0, 0.f) + EPS;
            float lo1 = fmaxf(x1, 0.f) + EPS, hi1 = fmaxf(1.f - x1, 0.f) + EPS;
            float lo2 = fmaxf(x2, 0.f) + EPS, hi2 = fmaxf(1.f - x2, 0.f) + EPS;
            float lo3 = fmaxf(x3, 0.f) + EPS, hi3 = fmaxf(1.f - x3, 0.f) + EPS;
            float lo4 = fmaxf(x4, 0.f) + EPS, hi4 = fmaxf(1.f - x4, 0.f) + EPS;
            float lo5 = fmaxf(x5, 0.f) + EPS, hi5 = fmaxf(1.f - x5, 0.f) + EPS;

            float m01[4] = {lo0 * lo1, lo0 * hi1, hi0 * lo1, hi0 * hi1};
            float m23[4] = {lo2 * lo3, lo2 * hi3, hi2 * lo3, hi2 * hi3};
            float m45[4] = {lo4 * lo5, lo4 * hi5, hi4 * lo5, hi4 * hi5};

            // acc = sum_p m01[p] * sum_q m23[q] * sum_r m45[r]*g[p*16+q*4+r]
            float acc = 0.f;
#pragma unroll
            for (int p = 0; p < 4; ++p) {
                float accp = 0.f;
#pragma unroll
                for (int q = 0; q < 4; ++q) {
                    const int base = p * 16 + q * 4;
                    float inner = m45[0] * g[base + 0];
                    inner = fmaf(m45[1], g[base + 1], inner);
                    inner = fmaf(m45[2], g[base + 2], inner);
                    inner = fmaf(m45[3], g[base + 3], inner);
                    accp = fmaf(m23[q], inner, accp);
                }
                acc = fmaf(m01[p], accp, acc);
            }
            __builtin_nontemporal_store(acc, op + (size_t)(s * B_SUB + bl) * DDIM);
        }
        __syncthreads();
        if (s + 1 < NSTAGE) {
            WRITE_STAGE();
            __syncthreads();
        }
    }
}

extern "C" void kernel_launch(void* const* d_in, const int* in_sizes, int n_in,
                              void* d_out, int out_size, void* d_ws, size_t ws_size,
                              hipStream_t stream) {
    const float* inputs = (const float*)d_in[0];
    const float* lut    = (const float*)d_in[1];
    // d_in[2] (p_q_2_lut_table) is a deterministic bit-selection table whose
    // structure is folded into the product tree above.
    float* out = (float*)d_out;

    dim3 grid(DDIM / DPB, BDIM / B_CHUNK);   // (8, 128) = 1024 blocks
    dim3 block(256);
    lut_layer_kernel<<<grid, block, 0, stream>>>(inputs, lut, out);
}

// Round 3
// 179.085 us; speedup vs baseline: 1.4432x; 1.0354x over previous
//
#include <hip/hip_runtime.h>

#define DDIM 2048
#define BDIM 2048
#define EPS 1e-7f
#define DPB 256                 // d-values per block (one per thread)
#define B_CHUNK 8               // b-values per block
#define B_SUB 4                 // b-rows staged in LDS per stage
#define NSTAGE (B_CHUNK / B_SUB)
#define GATE_BYTES (DDIM * 64 * sizeof(float))

// ---- kernel 1: gate[d][i] = sigmoid(50 * lut[d][i]) (512 KB, L2-resident) ----
__global__ __launch_bounds__(256)
void gate_kernel(const float* __restrict__ lut, float* __restrict__ gate) {
    const int i = blockIdx.x * 256 + threadIdx.x;          // float4 index
    float4 v = reinterpret_cast<const float4*>(lut)[i];
    float4 r;
    r.x = 1.0f / (1.0f + __expf(-50.0f * v.x));
    r.y = 1.0f / (1.0f + __expf(-50.0f * v.y));
    r.z = 1.0f / (1.0f + __expf(-50.0f * v.z));
    r.w = 1.0f / (1.0f + __expf(-50.0f * v.w));
    reinterpret_cast<float4*>(gate)[i] = r;
}

// ---- kernel 2: main. Thread owns one d; gate row from ws (no transcendentals).
// Inputs staged to LDS with coalesced float4 loads, register-prefetched one
// stage ahead. B_CHUNK=8 -> 2048 blocks -> 6 blocks/CU (LDS-limited), 24 waves/CU.
__global__ __launch_bounds__(256)
void lut_layer_kernel(const float* __restrict__ inputs,
                      const float* __restrict__ gate,
                      float* __restrict__ out) {
    __shared__ float sbuf[B_SUB * DPB * 6];   // 24 KB
    const int t    = threadIdx.x;
    const int lane = t & 63;
    const int wrow = t >> 6;                  // wave index = staged b-row
    const int d0   = blockIdx.x * DPB;
    const int b0   = blockIdx.y * B_CHUNK;

    float g[64];
    {
        const float4* gr = reinterpret_cast<const float4*>(gate + (size_t)(d0 + t) * 64);
#pragma unroll
        for (int k = 0; k < 16; ++k) {
            float4 v = gr[k];
            g[4*k+0] = v.x; g[4*k+1] = v.y; g[4*k+2] = v.z; g[4*k+3] = v.w;
        }
    }

    const float* gbase = inputs + ((size_t)b0 * DDIM + d0) * 6;
    const size_t rstr  = (size_t)DDIM * 6;

    float4 pf[6];
    auto LOAD_STAGE = [&](int s) {
#pragma unroll
        for (int r = 0; r < 6; ++r)
            pf[r] = *reinterpret_cast<const float4*>(
                gbase + (size_t)(s * B_SUB + wrow) * rstr + ((r * 64 + lane) << 2));
    };
    auto WRITE_STAGE = [&]() {
#pragma unroll
        for (int r = 0; r < 6; ++r)
            *reinterpret_cast<float4*>(
                &sbuf[wrow * (DPB * 6) + ((r * 64 + lane) << 2)]) = pf[r];
    };

    LOAD_STAGE(0);
    WRITE_STAGE();
    __syncthreads();

    float* op = out + (size_t)b0 * DDIM + d0 + t;

    for (int s = 0; s < NSTAGE; ++s) {
        if (s + 1 < NSTAGE) LOAD_STAGE(s + 1);

#pragma unroll
        for (int bl = 0; bl < B_SUB; ++bl) {
            const float* e = &sbuf[bl * (DPB * 6) + t * 6];
            float x0 = e[0], x1 = e[1], x2 = e[2], x3 = e[3], x4 = e[4], x5 = e[5];

            float lo0 = fmaxf(x0, 0.f) + EPS, hi0 = fmaxf(1.f - x0, 0.f) + EPS;
            float lo1 = fmaxf(x1, 0.f) + EPS, hi1 = fmaxf(1.f - x1, 0.f) + EPS;
            float lo2 = fmaxf(x2, 0.f) + EPS, hi2 = fmaxf(1.f - x2, 0.f) + EPS;
            float lo3 = fmaxf(x3, 0.f) + EPS, hi3 = fmaxf(1.f - x3, 0.f) + EPS;
            float lo4 = fmaxf(x4, 0.f) + EPS, hi4 = fmaxf(1.f - x4, 0.f) + EPS;
            float lo5 = fmaxf(x5, 0.f) + EPS, hi5 = fmaxf(1.f - x5, 0.f) + EPS;

            float m01[4] = {lo0 * lo1, lo0 * hi1, hi0 * lo1, hi0 * hi1};
            float m23[4] = {lo2 * lo3, lo2 * hi3, hi2 * lo3, hi2 * hi3};
            float m45[4] = {lo4 * lo5, lo4 * hi5, hi4 * lo5, hi4 * hi5};

            float acc = 0.f;
#pragma unroll
            for (int p = 0; p < 4; ++p) {
                float accp = 0.f;
#pragma unroll
                for (int q = 0; q < 4; ++q) {
                    const int base = p * 16 + q * 4;
                    float inner = m45[0] * g[base + 0];
                    inner = fmaf(m45[1], g[base + 1], inner);
                    inner = fmaf(m45[2], g[base + 2], inner);
                    inner = fmaf(m45[3], g[base + 3], inner);
                    accp = fmaf(m23[q], inner, accp);
                }
                acc = fmaf(m01[p], accp, acc);
            }
            __builtin_nontemporal_store(acc, op + (size_t)(s * B_SUB + bl) * DDIM);
        }
        __syncthreads();
        if (s + 1 < NSTAGE) {
            WRITE_STAGE();
            __syncthreads();
        }
    }
}

// ---- fallback (ws too small): round-2 kernel with inline sigmoid ----
__global__ __launch_bounds__(256)
void lut_layer_fallback(const float* __restrict__ inputs,
                        const float* __restrict__ lut,
                        float* __restrict__ out) {
    __shared__ float sbuf[B_SUB * DPB * 6];
    const int t = threadIdx.x, lane = t & 63, wrow = t >> 6;
    const int d0 = blockIdx.x * DPB, b0 = blockIdx.y * B_CHUNK;
    float g[64];
    const float4* lr = reinterpret_cast<const float4*>(lut + (size_t)(d0 + t) * 64);
#pragma unroll
    for (int k = 0; k < 16; ++k) {
        float4 v = lr[k];
        g[4*k+0] = 1.0f / (1.0f + __expf(-50.0f * v.x));
        g[4*k+1] = 1.0f / (1.0f + __expf(-50.0f * v.y));
        g[4*k+2] = 1.0f / (1.0f + __expf(-50.0f * v.z));
        g[4*k+3] = 1.0f / (1.0f + __expf(-50.0f * v.w));
    }
    const float* gbase = inputs + ((size_t)b0 * DDIM + d0) * 6;
    const size_t rstr = (size_t)DDIM * 6;
    float4 pf[6];
    auto LOAD_STAGE = [&](int s) {
#pragma unroll
        for (int r = 0; r < 6; ++r)
            pf[r] = *reinterpret_cast<const float4*>(
                gbase + (size_t)(s * B_SUB + wrow) * rstr + ((r * 64 + lane) << 2));
    };
    auto WRITE_STAGE = [&]() {
#pragma unroll
        for (int r = 0; r < 6; ++r)
            *reinterpret_cast<float4*>(&sbuf[wrow * (DPB * 6) + ((r * 64 + lane) << 2)]) = pf[r];
    };
    LOAD_STAGE(0); WRITE_STAGE(); __syncthreads();
    float* op = out + (size_t)b0 * DDIM + d0 + t;
    for (int s = 0; s < NSTAGE; ++s) {
        if (s + 1 < NSTAGE) LOAD_STAGE(s + 1);
#pragma unroll
        for (int bl = 0; bl < B_SUB; ++bl) {
            const float* e = &sbuf[bl * (DPB * 6) + t * 6];
            float x0 = e[0], x1 = e[1], x2 = e[2], x3 = e[3], x4 = e[4], x5 = e[5];
            float lo0 = fmaxf(x0, 0.f) + EPS, hi0 = fmaxf(1.f - x0, 0.f) + EPS;
            float lo1 = fmaxf(x1, 0.f) + EPS, hi1 = fmaxf(1.f - x1, 0.f) + EPS;
            float lo2 = fmaxf(x2, 0.f) + EPS, hi2 = fmaxf(1.f - x2, 0.f) + EPS;
            float lo3 = fmaxf(x3, 0.f) + EPS, hi3 = fmaxf(1.f - x3, 0.f) + EPS;
            float lo4 = fmaxf(x4, 0.f) + EPS, hi4 = fmaxf(1.f - x4, 0.f) + EPS;
            float lo5 = fmaxf(x5, 0.f) + EPS, hi5 = fmaxf(1.f - x5, 0.f) + EPS;
            float m01[4] = {lo0*lo1, lo0*hi1, hi0*lo1, hi0*hi1};
            float m23[4] = {lo2*lo3, lo2*hi3, hi2*lo3, hi2*hi3};
            float m45[4] = {lo4*lo5, lo4*hi5, hi4*lo5, hi4*hi5};
            float acc = 0.f;
#pragma unroll
            for (int p = 0; p < 4; ++p) {
                float accp = 0.f;
#pragma unroll
                for (int q = 0; q < 4; ++q) {
                    const int base = p * 16 + q * 4;
                    float inner = m45[0] * g[base+0];
                    inner = fmaf(m45[1], g[base+1], inner);
                    inner = fmaf(m45[2], g[base+2], inner);
                    inner = fmaf(m45[3], g[base+3], inner);
                    accp = fmaf(m23[q], inner, accp);
                }
                acc = fmaf(m01[p], accp, acc);
            }
            __builtin_nontemporal_store(acc, op + (size_t)(s * B_SUB + bl) * DDIM);
        }
        __syncthreads();
        if (s + 1 < NSTAGE) { WRITE_STAGE(); __syncthreads(); }
    }
}

extern "C" void kernel_launch(void* const* d_in, const int* in_sizes, int n_in,
                              void* d_out, int out_size, void* d_ws, size_t ws_size,
                              hipStream_t stream) {
    const float* inputs = (const float*)d_in[0];
    const float* lut    = (const float*)d_in[1];
    float* out = (float*)d_out;
    dim3 grid(DDIM / DPB, BDIM / B_CHUNK);   // (8, 256) = 2048 blocks
    dim3 block(256);

    if (ws_size >= GATE_BYTES) {
        float* gate = (float*)d_ws;
        gate_kernel<<<dim3(DDIM * 64 / 4 / 256), block, 0, stream>>>(lut, gate);
        lut_layer_kernel<<<grid, block, 0, stream>>>(inputs, gate, out);
    } else {
        lut_layer_fallback<<<grid, block, 0, stream>>>(inputs, lut, out);
    }
}